// Round 14
// baseline (750.191 us; speedup 1.0000x reference)
//
#include <hip/hip_runtime.h>
#include <cmath>

// SimpleHeteroGNN on MI355X — Round 14.
// R13 = best (746us). fill_lin is random-line HBM-bound (~182us plateau after
// 3 rounds of tuning: 205->186->182). This round attacks the latency-bound
// gather kernels' MLP depth only: movie agg unroll 16, user/uu agg unroll 8,
// ep_edge full-unroll (8 edges in flight per quarter). No structural change.

#define NUSR 100000
#define NMOV 20000
#define NEDG 1000000
#define NEUU 500000
#define DH 128

// padded adjacency capacities (degree means 50/10/5, std 7.1/3.2/2.2; guarded)
#define CAPM 96
#define CAPU 32
#define CAPUU 24

// XCD-binned fill geometry (mixed single-pass)
#define FCH 2048
#define NCH_R ((NEDG + FCH - 1) / FCH)  // 489
#define NCB (8 * NCH_R)                 // 3912 fill blocks
#define MRNG (NMOV / 8)
#define URNG (NUSR / 8)

// lin block ranges
#define GLU ((NUSR + 127) / 128)        // 782
#define GLM ((NMOV + 127) / 128)        // 157

typedef unsigned short ushort_t;
typedef __attribute__((ext_vector_type(8))) short short8;
typedef __attribute__((ext_vector_type(4))) float f32x4;

__device__ __forceinline__ ushort_t f2bf(float f) {
  unsigned u = __float_as_uint(f);
  u += 0x7FFFu + ((u >> 16) & 1u);
  return (ushort_t)(u >> 16);
}
__device__ __forceinline__ void bf8_to_f32(int4 v, float* f) {
  unsigned a = (unsigned)v.x, b = (unsigned)v.y, c = (unsigned)v.z, d = (unsigned)v.w;
  f[0] = __uint_as_float(a << 16); f[1] = __uint_as_float(a & 0xFFFF0000u);
  f[2] = __uint_as_float(b << 16); f[3] = __uint_as_float(b & 0xFFFF0000u);
  f[4] = __uint_as_float(c << 16); f[5] = __uint_as_float(c & 0xFFFF0000u);
  f[6] = __uint_as_float(d << 16); f[7] = __uint_as_float(d & 0xFFFF0000u);
}
__device__ __forceinline__ int ntl(const int* p) { return __builtin_nontemporal_load(p); }
__device__ __forceinline__ ushort_t ntl(const ushort_t* p) { return __builtin_nontemporal_load(p); }

// ---------- fused weight prep + BN params + cnt zero ----------
struct PrepArgs {
  const float* Wl[6];
  const float* Wr[6];
};
__global__ __launch_bounds__(256) void prep_all_k(
    PrepArgs pa, ushort_t* __restrict__ Wt,
    const float* __restrict__ W_user, const float* __restrict__ W_movie,
    ushort_t* __restrict__ WtU, ushort_t* __restrict__ WtM,
    const float* __restrict__ p1b, const float* __restrict__ gamma,
    const float* __restrict__ beta, const float* __restrict__ mean,
    const float* __restrict__ var,
    float* __restrict__ SEP, float* __restrict__ TEP,
    int* __restrict__ cntbuf)
{
  int blk = blockIdx.x;
  if (blk < 768) {
    int wi = blk >> 7;
    int idx = (blk & 127) * 256 + threadIdx.x;
    int n = idx >> 8, k = idx & 255;
    const float* Wl = pa.Wl[wi];
    const float* Wr = pa.Wr[wi];
    float v = (k < DH) ? Wl[k * DH + n] : Wr[(k - DH) * DH + n];
    Wt[(size_t)wi * 32768 + n * 256 + k] = f2bf(v);
  } else if (blk < 800) {
    int idx = (blk - 768) * 256 + threadIdx.x;
    int n = idx >> 6, k = idx & 63;
    WtU[n * 64 + k] = f2bf(W_user[k * DH + n]);
  } else if (blk < 864) {
    int idx = (blk - 800) * 256 + threadIdx.x;
    int n = idx >> 7, k = idx & 127;
    WtM[n * 128 + k] = f2bf(W_movie[k * DH + n]);
  } else if (blk == 864) {
    int f = threadIdx.x;
    if (f < DH) {
      float sc = gamma[f] * rsqrtf(var[f] + 1e-5f);
      SEP[f] = sc;
      TEP[f] = (p1b[f] - mean[f]) * sc + beta[f];
    }
  } else {
    int idx = (blk - 865) * 256 + threadIdx.x;  // int4 index
    if (idx < (NMOV + 2 * NUSR) / 4) ((int4*)cntbuf)[idx] = make_int4(0, 0, 0, 0);
  }
}

// ---------- lin GEMM body (fp32 A converted in-register) ----------
template <int K>
__device__ __forceinline__ void lin_body(
    int lblk, const float* __restrict__ X, const ushort_t* __restrict__ Wt,
    const float* __restrict__ b, ushort_t* __restrict__ Y, int N)
{
  const int wave = threadIdx.x >> 6;
  const int lane = threadIdx.x & 63;
  const int row0 = (lblk * 4 + wave) * 32;
  if (row0 >= N) return;
  const int lm = lane & 15;
  const int koff = (lane >> 4) * 8;

  f32x4 acc[2][8];
#pragma unroll
  for (int a = 0; a < 2; ++a)
#pragma unroll
    for (int nt = 0; nt < 8; ++nt) acc[a][nt] = (f32x4){0.f, 0.f, 0.f, 0.f};

#pragma unroll
  for (int ks = 0; ks < K / 32; ++ks) {
    short8 af[2];
#pragma unroll
    for (int a = 0; a < 2; ++a) {
      const float* p = X + (size_t)(row0 + a * 16 + lm) * K + ks * 32 + koff;
      float4 v0 = *(const float4*)p;
      float4 v1 = *(const float4*)(p + 4);
      short8 s;
      s[0] = (short)f2bf(v0.x); s[1] = (short)f2bf(v0.y);
      s[2] = (short)f2bf(v0.z); s[3] = (short)f2bf(v0.w);
      s[4] = (short)f2bf(v1.x); s[5] = (short)f2bf(v1.y);
      s[6] = (short)f2bf(v1.z); s[7] = (short)f2bf(v1.w);
      af[a] = s;
    }
#pragma unroll
    for (int nt = 0; nt < 8; ++nt) {
      short8 bf = *(const short8*)&Wt[(nt * 16 + lm) * K + ks * 32 + koff];
      acc[0][nt] = __builtin_amdgcn_mfma_f32_16x16x32_bf16(af[0], bf, acc[0][nt], 0, 0, 0);
      acc[1][nt] = __builtin_amdgcn_mfma_f32_16x16x32_bf16(af[1], bf, acc[1][nt], 0, 0, 0);
    }
  }

  const int quad = lane >> 4;
#pragma unroll
  for (int nt = 0; nt < 8; ++nt) {
    int f = nt * 16 + lm;
    float bv = b[f];
#pragma unroll
    for (int a = 0; a < 2; ++a) {
#pragma unroll
      for (int reg = 0; reg < 4; ++reg) {
        int r = row0 + a * 16 + quad * 4 + reg;
        Y[(size_t)r * DH + f] = f2bf(fmaxf(acc[a][nt][reg] + bv, 0.f));
      }
    }
  }
}

// ---------- fused: XCD-binned mixed direct fill + input linears ----------
__global__ __launch_bounds__(256) void fill_lin_k(
    const int* __restrict__ rsrc, const int* __restrict__ rdst,
    const int* __restrict__ usrc, const int* __restrict__ udst,
    int* __restrict__ cnt_m, int* __restrict__ cnt_u, int* __restrict__ cnt_uu,
    int* __restrict__ col_m, ushort_t* __restrict__ col_u, int* __restrict__ col_uu,
    const float* __restrict__ user_feat, const ushort_t* __restrict__ WtU,
    const float* __restrict__ b_user, ushort_t* __restrict__ ux,
    const float* __restrict__ movie_feat, const ushort_t* __restrict__ WtM,
    const float* __restrict__ b_movie, ushort_t* __restrict__ mx)
{
  const int blk = blockIdx.x;
  if (blk < NCB) {
    const int xr = blk & 7;
    const int c = blk >> 3;
    const int mlo = xr * MRNG, mhi = mlo + MRNG;
    const int ulo = xr * URNG, uhi = ulo + URNG;
    const int base = c * FCH;
#pragma unroll
    for (int i = 0; i < 8; ++i) {
      int e = base + i * 256 + threadIdx.x;
      if (e < NEDG) {
        int s = ntl(&rsrc[e]), d = ntl(&rdst[e]);
        if (d >= mlo && d < mhi) {
          int o = atomicAdd(&cnt_m[d], 1);
          if (o < CAPM) col_m[d * CAPM + o] = s;
        }
        if (s >= ulo && s < uhi) {
          int o = atomicAdd(&cnt_u[s], 1);
          if (o < CAPU) col_u[s * CAPU + o] = (ushort_t)d;
        }
      }
      if (e < NEUU) {
        int s = ntl(&usrc[e]), d = ntl(&udst[e]);
        if (d >= ulo && d < uhi) {
          int o = atomicAdd(&cnt_uu[d], 1);
          if (o < CAPUU) col_uu[d * CAPUU + o] = s;
        }
      }
    }
  } else if (blk < NCB + GLU) {
    lin_body<64>(blk - NCB, user_feat, WtU, b_user, ux, NUSR);
  } else {
    lin_body<128>(blk - NCB - GLU, movie_feat, WtM, b_movie, mx, NMOV);
  }
}

// ---------- gather-mean over padded adjacency: 4 rows/wave (quarter each) ----------
// UNR: max unroll batch (16 for movies, 8 for users/uu) for load MLP depth.
template <typename CT, int CAP, int UNR>
__global__ __launch_bounds__(256) void agg_mean4_k(
    const ushort_t* __restrict__ x, const int* __restrict__ cnt,
    const CT* __restrict__ col, ushort_t* __restrict__ out, int N)
{
  const int wave = threadIdx.x >> 6;
  const int lane = threadIdx.x & 63;
  const int lm = lane & 15, q = lane >> 4;
  const int row = blockIdx.x * 16 + wave * 4 + q;
  if (row >= N) return;
  const int deg = cnt[row];
  const int e = (deg < CAP) ? deg : CAP;
  const CT* crow = col + (size_t)row * CAP;
  float a[8];
#pragma unroll
  for (int j = 0; j < 8; ++j) a[j] = 0.f;
  int i = 0;
  if (UNR >= 16) {
    for (; i + 15 < e; i += 16) {
      int4 v[16];
#pragma unroll
      for (int u = 0; u < 16; ++u) {
        int s = (int)ntl(&crow[i + u]);
        v[u] = *(const int4*)(x + (size_t)s * DH + lm * 8);
      }
#pragma unroll
      for (int u = 0; u < 16; ++u) {
        float f0[8];
        bf8_to_f32(v[u], f0);
#pragma unroll
        for (int j = 0; j < 8; ++j) a[j] += f0[j];
      }
    }
  }
  if (UNR >= 8) {
    for (; i + 7 < e; i += 8) {
      int4 v[8];
#pragma unroll
      for (int u = 0; u < 8; ++u) {
        int s = (int)ntl(&crow[i + u]);
        v[u] = *(const int4*)(x + (size_t)s * DH + lm * 8);
      }
#pragma unroll
      for (int u = 0; u < 8; ++u) {
        float f0[8];
        bf8_to_f32(v[u], f0);
#pragma unroll
        for (int j = 0; j < 8; ++j) a[j] += f0[j];
      }
    }
  }
  for (; i + 3 < e; i += 4) {
    int s0 = (int)ntl(&crow[i]), s1 = (int)ntl(&crow[i + 1]);
    int s2 = (int)ntl(&crow[i + 2]), s3 = (int)ntl(&crow[i + 3]);
    int4 v0 = *(const int4*)(x + (size_t)s0 * DH + lm * 8);
    int4 v1 = *(const int4*)(x + (size_t)s1 * DH + lm * 8);
    int4 v2 = *(const int4*)(x + (size_t)s2 * DH + lm * 8);
    int4 v3 = *(const int4*)(x + (size_t)s3 * DH + lm * 8);
    float f0[8], f1[8], f2[8], f3[8];
    bf8_to_f32(v0, f0); bf8_to_f32(v1, f1); bf8_to_f32(v2, f2); bf8_to_f32(v3, f3);
#pragma unroll
    for (int j = 0; j < 8; ++j) a[j] += (f0[j] + f1[j]) + (f2[j] + f3[j]);
  }
  for (; i < e; ++i) {
    int4 v0 = *(const int4*)(x + (size_t)(int)ntl(&crow[i]) * DH + lm * 8);
    float f0[8];
    bf8_to_f32(v0, f0);
#pragma unroll
    for (int j = 0; j < 8; ++j) a[j] += f0[j];
  }
  float inv = 1.f / (float)(deg > 1 ? deg : 1);
  unsigned p0 = f2bf(a[0] * inv) | ((unsigned)f2bf(a[1] * inv) << 16);
  unsigned p1 = f2bf(a[2] * inv) | ((unsigned)f2bf(a[3] * inv) << 16);
  unsigned p2 = f2bf(a[4] * inv) | ((unsigned)f2bf(a[5] * inv) << 16);
  unsigned p3 = f2bf(a[6] * inv) | ((unsigned)f2bf(a[7] * inv) << 16);
  *(int4*)(out + (size_t)row * DH + lm * 8) = make_int4(p0, p1, p2, p3);
}

// ---------- SAGE update GEMM (no LDS): out = relu([A0|A1] @ WtT + bl) ----------
__global__ __launch_bounds__(256) void sage_mfma_k(
    const ushort_t* __restrict__ A0, const ushort_t* __restrict__ A1,
    const ushort_t* __restrict__ Wt, const float* __restrict__ bl,
    ushort_t* __restrict__ out, int N)
{
  const int wave = threadIdx.x >> 6;
  const int lane = threadIdx.x & 63;
  const int row0 = (blockIdx.x * 4 + wave) * 32;
  if (row0 >= N) return;
  const int lm = lane & 15;
  const int koff = (lane >> 4) * 8;

  size_t abase[2];
#pragma unroll
  for (int a = 0; a < 2; ++a) abase[a] = (size_t)(row0 + a * 16 + lm) * DH;

  f32x4 acc[2][8];
#pragma unroll
  for (int a = 0; a < 2; ++a)
#pragma unroll
    for (int nt = 0; nt < 8; ++nt) acc[a][nt] = (f32x4){0.f, 0.f, 0.f, 0.f};

#pragma unroll
  for (int ks = 0; ks < 8; ++ks) {
    short8 af[2];
#pragma unroll
    for (int a = 0; a < 2; ++a) {
      const ushort_t* p = (ks < 4) ? (A0 + abase[a] + ks * 32 + koff)
                                   : (A1 + abase[a] + (ks - 4) * 32 + koff);
      af[a] = *(const short8*)p;
    }
#pragma unroll
    for (int nt = 0; nt < 8; ++nt) {
      short8 bf = *(const short8*)&Wt[(nt * 16 + lm) * 256 + ks * 32 + koff];
      acc[0][nt] = __builtin_amdgcn_mfma_f32_16x16x32_bf16(af[0], bf, acc[0][nt], 0, 0, 0);
      acc[1][nt] = __builtin_amdgcn_mfma_f32_16x16x32_bf16(af[1], bf, acc[1][nt], 0, 0, 0);
    }
  }

  const int quad = lane >> 4;
#pragma unroll
  for (int nt = 0; nt < 8; ++nt) {
    int f = nt * 16 + lm;
    float bv = bl[f];
#pragma unroll
    for (int a = 0; a < 2; ++a) {
#pragma unroll
      for (int reg = 0; reg < 4; ++reg) {
        int r = row0 + a * 16 + quad * 4 + reg;
        out[(size_t)r * DH + f] = f2bf(fmaxf(acc[a][nt][reg] + bv, 0.f));
      }
    }
  }
}

// ---------- fused projection GEMMs: pu = ux@Wu, pm = mx@Wm ----------
__device__ __forceinline__ void proj_body(
    int lblk, const ushort_t* __restrict__ A, const ushort_t* __restrict__ Wt,
    int kofs, ushort_t* __restrict__ out, int N)
{
  const int wave = threadIdx.x >> 6;
  const int lane = threadIdx.x & 63;
  const int row0 = (lblk * 4 + wave) * 32;
  if (row0 >= N) return;
  const int lm = lane & 15;
  const int koff = (lane >> 4) * 8;

  size_t abase[2];
#pragma unroll
  for (int a = 0; a < 2; ++a) abase[a] = (size_t)(row0 + a * 16 + lm) * DH;

  f32x4 acc[2][8];
#pragma unroll
  for (int a = 0; a < 2; ++a)
#pragma unroll
    for (int nt = 0; nt < 8; ++nt) acc[a][nt] = (f32x4){0.f, 0.f, 0.f, 0.f};

#pragma unroll
  for (int ks = 0; ks < 4; ++ks) {
    short8 af[2];
#pragma unroll
    for (int a = 0; a < 2; ++a) af[a] = *(const short8*)(A + abase[a] + ks * 32 + koff);
#pragma unroll
    for (int nt = 0; nt < 8; ++nt) {
      short8 bf = *(const short8*)&Wt[(nt * 16 + lm) * 256 + kofs + ks * 32 + koff];
      acc[0][nt] = __builtin_amdgcn_mfma_f32_16x16x32_bf16(af[0], bf, acc[0][nt], 0, 0, 0);
      acc[1][nt] = __builtin_amdgcn_mfma_f32_16x16x32_bf16(af[1], bf, acc[1][nt], 0, 0, 0);
    }
  }

  const int quad = lane >> 4;
#pragma unroll
  for (int nt = 0; nt < 8; ++nt) {
    int f = nt * 16 + lm;
#pragma unroll
    for (int a = 0; a < 2; ++a) {
#pragma unroll
      for (int reg = 0; reg < 4; ++reg) {
        int r = row0 + a * 16 + quad * 4 + reg;
        out[(size_t)r * DH + f] = f2bf(acc[a][nt][reg]);
      }
    }
  }
}

__global__ __launch_bounds__(256) void proj2_k(
    const ushort_t* __restrict__ ux, const ushort_t* __restrict__ mx,
    const ushort_t* __restrict__ Wt, ushort_t* __restrict__ pu,
    ushort_t* __restrict__ pm, int gmU)
{
  if ((int)blockIdx.x < gmU) proj_body(blockIdx.x, ux, Wt, 0, pu, NUSR);
  else proj_body(blockIdx.x - gmU, mx, Wt, DH, pm, NMOV);
}

// ---------- edge-parallel predictor: quarter-wave per edge, EPQ=8, full unroll ----------
#define EPQ 8
__global__ __launch_bounds__(256) void ep_edge_k(
    const ushort_t* __restrict__ pu, const ushort_t* __restrict__ pm,
    const int* __restrict__ esrc, const int* __restrict__ edst,
    const float* __restrict__ SEP, const float* __restrict__ TEP,
    const float* __restrict__ p2W, const float* __restrict__ p2b,
    float* __restrict__ out, int nE)
{
  const int lm = threadIdx.x & 15;
  const long tq = ((long)blockIdx.x * 256 + threadIdx.x) >> 4;
  const int f0 = lm * 8;

  float S[8], T8[8], w2[8];
#pragma unroll
  for (int j = 0; j < 8; ++j) {
    S[j] = SEP[f0 + j];
    T8[j] = TEP[f0 + j];
    w2[j] = p2W[f0 + j];
  }
  const float bias2 = p2b[0];

  const long e0 = tq * EPQ;
#pragma unroll
  for (int i = 0; i < EPQ; ++i) {
    long e = e0 + i;
    if (e >= nE) break;
    int s = ntl(&esrc[e]), d = ntl(&edst[e]);
    int4 uv = *(const int4*)(pu + (size_t)s * DH + f0);
    int4 mv = *(const int4*)(pm + (size_t)d * DH + f0);
    float fu[8], fm[8];
    bf8_to_f32(uv, fu); bf8_to_f32(mv, fm);
    float p = 0.f;
#pragma unroll
    for (int j = 0; j < 8; ++j) {
      float h = fmaxf(fmaf(fu[j] + fm[j], S[j], T8[j]), 0.f);
      p = fmaf(h, w2[j], p);
    }
    p += __shfl_xor(p, 1, 16);
    p += __shfl_xor(p, 2, 16);
    p += __shfl_xor(p, 4, 16);
    p += __shfl_xor(p, 8, 16);
    if (lm == 0) out[e] = 4.f / (1.f + expf(-(p + bias2))) + 1.f;
  }
}

extern "C" void kernel_launch(void* const* d_in, const int* in_sizes, int n_in,
                              void* d_out, int out_size, void* d_ws, size_t ws_size,
                              hipStream_t stream)
{
  const float* user_feat = (const float*)d_in[0];
  const float* movie_feat = (const float*)d_in[1];
  const float* W_user = (const float*)d_in[2];
  const float* b_user = (const float*)d_in[3];
  const float* W_movie = (const float*)d_in[4];
  const float* b_movie = (const float*)d_in[5];
  const float* u2m1_Wl = (const float*)d_in[6];
  const float* u2m1_bl = (const float*)d_in[7];
  const float* u2m1_Wr = (const float*)d_in[8];
  const float* m2u1_Wl = (const float*)d_in[9];
  const float* m2u1_bl = (const float*)d_in[10];
  const float* m2u1_Wr = (const float*)d_in[11];
  const float* u2m2_Wl = (const float*)d_in[12];
  const float* u2m2_bl = (const float*)d_in[13];
  const float* u2m2_Wr = (const float*)d_in[14];
  const float* m2u2_Wl = (const float*)d_in[15];
  const float* m2u2_bl = (const float*)d_in[16];
  const float* m2u2_Wr = (const float*)d_in[17];
  const float* u2u_Wl = (const float*)d_in[18];
  const float* u2u_bl = (const float*)d_in[19];
  const float* u2u_Wr = (const float*)d_in[20];
  const float* p1_W = (const float*)d_in[21];
  const float* p1_b = (const float*)d_in[22];
  const float* bn_gamma = (const float*)d_in[23];
  const float* bn_beta = (const float*)d_in[24];
  const float* bn_mean = (const float*)d_in[25];
  const float* bn_var = (const float*)d_in[26];
  const float* p2_W = (const float*)d_in[27];
  const float* p2_b = (const float*)d_in[28];
  const int* rated_src = (const int*)d_in[29];
  const int* rated_dst = (const int*)d_in[30];
  const int* uu_src = (const int*)d_in[31];
  const int* uu_dst = (const int*)d_in[32];

  // ---- workspace layout (~86 MB) ----
  ushort_t* ux = (ushort_t*)d_ws;                       // NU*128
  ushort_t* mx = ux + (size_t)NUSR * DH;                // NM*128
  ushort_t* agg = mx + (size_t)NMOV * DH;               // NU*128 (reused as pu)
  ushort_t* pm = agg + (size_t)NUSR * DH;               // NM*128
  ushort_t* Wt = pm + (size_t)NMOV * DH;                // 6 * 32768
  ushort_t* WtU = Wt + 6 * 32768;                       // 128*64
  ushort_t* WtM = WtU + 8192;                           // 128*128
  float* SEP = (float*)(WtM + 16384);                   // 128
  float* TEP = SEP + DH;                                // 128
  int* col_m = (int*)(TEP + DH);                        // NMOV*CAPM ints
  ushort_t* col_u = (ushort_t*)(col_m + (size_t)NMOV * CAPM);   // NUSR*CAPU ushorts
  int* col_uu = (int*)(col_u + (size_t)NUSR * CAPU);    // NUSR*CAPUU ints
  int* cntbuf = col_uu + (size_t)NUSR * CAPUU;          // NMOV+2*NUSR (16B-aligned)
  int* cnt_m = cntbuf;
  int* cnt_u = cntbuf + NMOV;
  int* cnt_uu = cntbuf + NMOV + NUSR;

  ushort_t* Wt_u2m1 = Wt + 0 * 32768;
  ushort_t* Wt_m2u1 = Wt + 1 * 32768;
  ushort_t* Wt_u2m2 = Wt + 2 * 32768;
  ushort_t* Wt_m2u2 = Wt + 3 * 32768;
  ushort_t* Wt_u2u  = Wt + 4 * 32768;
  ushort_t* Wt_p1   = Wt + 5 * 32768;
  ushort_t* pu = agg;  // alias: agg dead after last sage layer

  // ---- fused weight prep + BN params + cnt zero ----
  PrepArgs pa;
  pa.Wl[0] = u2m1_Wl; pa.Wr[0] = u2m1_Wr;
  pa.Wl[1] = m2u1_Wl; pa.Wr[1] = m2u1_Wr;
  pa.Wl[2] = u2m2_Wl; pa.Wr[2] = u2m2_Wr;
  pa.Wl[3] = m2u2_Wl; pa.Wr[3] = m2u2_Wr;
  pa.Wl[4] = u2u_Wl;  pa.Wr[4] = u2u_Wr;
  pa.Wl[5] = p1_W;    pa.Wr[5] = p1_W + DH * DH;
  prep_all_k<<<865 + (NMOV + 2 * NUSR) / 1024 + 1, 256, 0, stream>>>(
      pa, Wt, W_user, W_movie, WtU, WtM,
      p1_b, bn_gamma, bn_beta, bn_mean, bn_var, SEP, TEP, cntbuf);

  // ---- fused direct fill + input linears (one atomic pass) ----
  fill_lin_k<<<NCB + GLU + GLM, 256, 0, stream>>>(
      rated_src, rated_dst, uu_src, uu_dst, cnt_m, cnt_u, cnt_uu,
      col_m, col_u, col_uu,
      user_feat, WtU, b_user, ux, movie_feat, WtM, b_movie, mx);

  // ---- 5 SAGE layers (separate agg + GEMM) ----
  const int gaM = (NMOV + 15) / 16, gaU = (NUSR + 15) / 16;
  const int gmM = (NMOV + 127) / 128, gmU = (NUSR + 127) / 128;
  // u2m1
  agg_mean4_k<int, CAPM, 16><<<gaM, 256, 0, stream>>>(ux, cnt_m, col_m, agg, NMOV);
  sage_mfma_k<<<gmM, 256, 0, stream>>>(agg, mx, Wt_u2m1, u2m1_bl, mx, NMOV);
  // m2u1
  agg_mean4_k<ushort_t, CAPU, 8><<<gaU, 256, 0, stream>>>(mx, cnt_u, col_u, agg, NUSR);
  sage_mfma_k<<<gmU, 256, 0, stream>>>(agg, ux, Wt_m2u1, m2u1_bl, ux, NUSR);
  // u2m2
  agg_mean4_k<int, CAPM, 16><<<gaM, 256, 0, stream>>>(ux, cnt_m, col_m, agg, NMOV);
  sage_mfma_k<<<gmM, 256, 0, stream>>>(agg, mx, Wt_u2m2, u2m2_bl, mx, NMOV);
  // m2u2
  agg_mean4_k<ushort_t, CAPU, 8><<<gaU, 256, 0, stream>>>(mx, cnt_u, col_u, agg, NUSR);
  sage_mfma_k<<<gmU, 256, 0, stream>>>(agg, ux, Wt_m2u2, m2u2_bl, ux, NUSR);
  // u2u
  agg_mean4_k<int, CAPUU, 8><<<gaU, 256, 0, stream>>>(ux, cnt_uu, col_uu, agg, NUSR);
  sage_mfma_k<<<gmU, 256, 0, stream>>>(agg, ux, Wt_u2u, u2u_bl, ux, NUSR);

  // ---- factored edge MLP ----
  proj2_k<<<gmU + gmM, 256, 0, stream>>>(ux, mx, Wt_p1, pu, pm, gmU);
  ep_edge_k<<<(NEDG + 127) / 128, 256, 0, stream>>>(
      pu, pm, rated_src, rated_dst, SEP, TEP, p2_W, p2_b, (float*)d_out, NEDG);
}

// Round 15
// 717.379 us; speedup vs baseline: 1.0457x; 1.0457x over previous
//
#include <hip/hip_runtime.h>
#include <cmath>

// SimpleHeteroGNN on MI355X — Round 15.
// R14 post-mortem: deeper agg unrolls NEUTRAL (aggs are L2/L3-service bound,
// not MLP-depth bound). New theory: fill+lin fusion pollutes per-XCD L2 with
// 59MB of lin streams -> partial col-line evictions (139MB WRITE vs ~11MB
// payload; R7's unfused fill was 110us@116MB). This round: split fill and lin
// into separate dispatches (fill first, unpolluted). Everything else = R14.

#define NUSR 100000
#define NMOV 20000
#define NEDG 1000000
#define NEUU 500000
#define DH 128

// padded adjacency capacities (degree means 50/10/5, std 7.1/3.2/2.2; guarded)
#define CAPM 96
#define CAPU 32
#define CAPUU 24

// XCD-binned fill geometry (mixed single-pass)
#define FCH 2048
#define NCH_R ((NEDG + FCH - 1) / FCH)  // 489
#define NCB (8 * NCH_R)                 // 3912 fill blocks
#define MRNG (NMOV / 8)
#define URNG (NUSR / 8)

// lin block ranges
#define GLU ((NUSR + 127) / 128)        // 782
#define GLM ((NMOV + 127) / 128)        // 157

typedef unsigned short ushort_t;
typedef __attribute__((ext_vector_type(8))) short short8;
typedef __attribute__((ext_vector_type(4))) float f32x4;

__device__ __forceinline__ ushort_t f2bf(float f) {
  unsigned u = __float_as_uint(f);
  u += 0x7FFFu + ((u >> 16) & 1u);
  return (ushort_t)(u >> 16);
}
__device__ __forceinline__ void bf8_to_f32(int4 v, float* f) {
  unsigned a = (unsigned)v.x, b = (unsigned)v.y, c = (unsigned)v.z, d = (unsigned)v.w;
  f[0] = __uint_as_float(a << 16); f[1] = __uint_as_float(a & 0xFFFF0000u);
  f[2] = __uint_as_float(b << 16); f[3] = __uint_as_float(b & 0xFFFF0000u);
  f[4] = __uint_as_float(c << 16); f[5] = __uint_as_float(c & 0xFFFF0000u);
  f[6] = __uint_as_float(d << 16); f[7] = __uint_as_float(d & 0xFFFF0000u);
}
__device__ __forceinline__ int ntl(const int* p) { return __builtin_nontemporal_load(p); }
__device__ __forceinline__ ushort_t ntl(const ushort_t* p) { return __builtin_nontemporal_load(p); }

// ---------- fused weight prep + BN params + cnt zero ----------
struct PrepArgs {
  const float* Wl[6];
  const float* Wr[6];
};
__global__ __launch_bounds__(256) void prep_all_k(
    PrepArgs pa, ushort_t* __restrict__ Wt,
    const float* __restrict__ W_user, const float* __restrict__ W_movie,
    ushort_t* __restrict__ WtU, ushort_t* __restrict__ WtM,
    const float* __restrict__ p1b, const float* __restrict__ gamma,
    const float* __restrict__ beta, const float* __restrict__ mean,
    const float* __restrict__ var,
    float* __restrict__ SEP, float* __restrict__ TEP,
    int* __restrict__ cntbuf)
{
  int blk = blockIdx.x;
  if (blk < 768) {
    int wi = blk >> 7;
    int idx = (blk & 127) * 256 + threadIdx.x;
    int n = idx >> 8, k = idx & 255;
    const float* Wl = pa.Wl[wi];
    const float* Wr = pa.Wr[wi];
    float v = (k < DH) ? Wl[k * DH + n] : Wr[(k - DH) * DH + n];
    Wt[(size_t)wi * 32768 + n * 256 + k] = f2bf(v);
  } else if (blk < 800) {
    int idx = (blk - 768) * 256 + threadIdx.x;
    int n = idx >> 6, k = idx & 63;
    WtU[n * 64 + k] = f2bf(W_user[k * DH + n]);
  } else if (blk < 864) {
    int idx = (blk - 800) * 256 + threadIdx.x;
    int n = idx >> 7, k = idx & 127;
    WtM[n * 128 + k] = f2bf(W_movie[k * DH + n]);
  } else if (blk == 864) {
    int f = threadIdx.x;
    if (f < DH) {
      float sc = gamma[f] * rsqrtf(var[f] + 1e-5f);
      SEP[f] = sc;
      TEP[f] = (p1b[f] - mean[f]) * sc + beta[f];
    }
  } else {
    int idx = (blk - 865) * 256 + threadIdx.x;  // int4 index
    if (idx < (NMOV + 2 * NUSR) / 4) ((int4*)cntbuf)[idx] = make_int4(0, 0, 0, 0);
  }
}

// ---------- XCD-binned mixed direct fill (atomics + col stores ONLY) ----------
__global__ __launch_bounds__(256) void fill_k(
    const int* __restrict__ rsrc, const int* __restrict__ rdst,
    const int* __restrict__ usrc, const int* __restrict__ udst,
    int* __restrict__ cnt_m, int* __restrict__ cnt_u, int* __restrict__ cnt_uu,
    int* __restrict__ col_m, ushort_t* __restrict__ col_u, int* __restrict__ col_uu)
{
  const int xr = blockIdx.x & 7;
  const int c = blockIdx.x >> 3;
  const int mlo = xr * MRNG, mhi = mlo + MRNG;
  const int ulo = xr * URNG, uhi = ulo + URNG;
  const int base = c * FCH;
#pragma unroll
  for (int i = 0; i < 8; ++i) {
    int e = base + i * 256 + threadIdx.x;
    if (e < NEDG) {
      int s = ntl(&rsrc[e]), d = ntl(&rdst[e]);
      if (d >= mlo && d < mhi) {
        int o = atomicAdd(&cnt_m[d], 1);
        if (o < CAPM) col_m[d * CAPM + o] = s;
      }
      if (s >= ulo && s < uhi) {
        int o = atomicAdd(&cnt_u[s], 1);
        if (o < CAPU) col_u[s * CAPU + o] = (ushort_t)d;
      }
    }
    if (e < NEUU) {
      int s = ntl(&usrc[e]), d = ntl(&udst[e]);
      if (d >= ulo && d < uhi) {
        int o = atomicAdd(&cnt_uu[d], 1);
        if (o < CAPUU) col_uu[d * CAPUU + o] = s;
      }
    }
  }
}

// ---------- lin GEMM body (fp32 A converted in-register) ----------
template <int K>
__device__ __forceinline__ void lin_body(
    int lblk, const float* __restrict__ X, const ushort_t* __restrict__ Wt,
    const float* __restrict__ b, ushort_t* __restrict__ Y, int N)
{
  const int wave = threadIdx.x >> 6;
  const int lane = threadIdx.x & 63;
  const int row0 = (lblk * 4 + wave) * 32;
  if (row0 >= N) return;
  const int lm = lane & 15;
  const int koff = (lane >> 4) * 8;

  f32x4 acc[2][8];
#pragma unroll
  for (int a = 0; a < 2; ++a)
#pragma unroll
    for (int nt = 0; nt < 8; ++nt) acc[a][nt] = (f32x4){0.f, 0.f, 0.f, 0.f};

#pragma unroll
  for (int ks = 0; ks < K / 32; ++ks) {
    short8 af[2];
#pragma unroll
    for (int a = 0; a < 2; ++a) {
      const float* p = X + (size_t)(row0 + a * 16 + lm) * K + ks * 32 + koff;
      float4 v0 = *(const float4*)p;
      float4 v1 = *(const float4*)(p + 4);
      short8 s;
      s[0] = (short)f2bf(v0.x); s[1] = (short)f2bf(v0.y);
      s[2] = (short)f2bf(v0.z); s[3] = (short)f2bf(v0.w);
      s[4] = (short)f2bf(v1.x); s[5] = (short)f2bf(v1.y);
      s[6] = (short)f2bf(v1.z); s[7] = (short)f2bf(v1.w);
      af[a] = s;
    }
#pragma unroll
    for (int nt = 0; nt < 8; ++nt) {
      short8 bf = *(const short8*)&Wt[(nt * 16 + lm) * K + ks * 32 + koff];
      acc[0][nt] = __builtin_amdgcn_mfma_f32_16x16x32_bf16(af[0], bf, acc[0][nt], 0, 0, 0);
      acc[1][nt] = __builtin_amdgcn_mfma_f32_16x16x32_bf16(af[1], bf, acc[1][nt], 0, 0, 0);
    }
  }

  const int quad = lane >> 4;
#pragma unroll
  for (int nt = 0; nt < 8; ++nt) {
    int f = nt * 16 + lm;
    float bv = b[f];
#pragma unroll
    for (int a = 0; a < 2; ++a) {
#pragma unroll
      for (int reg = 0; reg < 4; ++reg) {
        int r = row0 + a * 16 + quad * 4 + reg;
        Y[(size_t)r * DH + f] = f2bf(fmaxf(acc[a][nt][reg] + bv, 0.f));
      }
    }
  }
}

// ---------- both input linears in one dispatch ----------
__global__ __launch_bounds__(256) void lin2_k(
    const float* __restrict__ user_feat, const ushort_t* __restrict__ WtU,
    const float* __restrict__ b_user, ushort_t* __restrict__ ux,
    const float* __restrict__ movie_feat, const ushort_t* __restrict__ WtM,
    const float* __restrict__ b_movie, ushort_t* __restrict__ mx)
{
  const int blk = blockIdx.x;
  if (blk < GLU) lin_body<64>(blk, user_feat, WtU, b_user, ux, NUSR);
  else lin_body<128>(blk - GLU, movie_feat, WtM, b_movie, mx, NMOV);
}

// ---------- gather-mean over padded adjacency: 4 rows/wave (quarter each) ----------
template <typename CT, int CAP, int UNR>
__global__ __launch_bounds__(256) void agg_mean4_k(
    const ushort_t* __restrict__ x, const int* __restrict__ cnt,
    const CT* __restrict__ col, ushort_t* __restrict__ out, int N)
{
  const int wave = threadIdx.x >> 6;
  const int lane = threadIdx.x & 63;
  const int lm = lane & 15, q = lane >> 4;
  const int row = blockIdx.x * 16 + wave * 4 + q;
  if (row >= N) return;
  const int deg = cnt[row];
  const int e = (deg < CAP) ? deg : CAP;
  const CT* crow = col + (size_t)row * CAP;
  float a[8];
#pragma unroll
  for (int j = 0; j < 8; ++j) a[j] = 0.f;
  int i = 0;
  if (UNR >= 16) {
    for (; i + 15 < e; i += 16) {
      int4 v[16];
#pragma unroll
      for (int u = 0; u < 16; ++u) {
        int s = (int)ntl(&crow[i + u]);
        v[u] = *(const int4*)(x + (size_t)s * DH + lm * 8);
      }
#pragma unroll
      for (int u = 0; u < 16; ++u) {
        float f0[8];
        bf8_to_f32(v[u], f0);
#pragma unroll
        for (int j = 0; j < 8; ++j) a[j] += f0[j];
      }
    }
  }
  if (UNR >= 8) {
    for (; i + 7 < e; i += 8) {
      int4 v[8];
#pragma unroll
      for (int u = 0; u < 8; ++u) {
        int s = (int)ntl(&crow[i + u]);
        v[u] = *(const int4*)(x + (size_t)s * DH + lm * 8);
      }
#pragma unroll
      for (int u = 0; u < 8; ++u) {
        float f0[8];
        bf8_to_f32(v[u], f0);
#pragma unroll
        for (int j = 0; j < 8; ++j) a[j] += f0[j];
      }
    }
  }
  for (; i + 3 < e; i += 4) {
    int s0 = (int)ntl(&crow[i]), s1 = (int)ntl(&crow[i + 1]);
    int s2 = (int)ntl(&crow[i + 2]), s3 = (int)ntl(&crow[i + 3]);
    int4 v0 = *(const int4*)(x + (size_t)s0 * DH + lm * 8);
    int4 v1 = *(const int4*)(x + (size_t)s1 * DH + lm * 8);
    int4 v2 = *(const int4*)(x + (size_t)s2 * DH + lm * 8);
    int4 v3 = *(const int4*)(x + (size_t)s3 * DH + lm * 8);
    float f0[8], f1[8], f2[8], f3[8];
    bf8_to_f32(v0, f0); bf8_to_f32(v1, f1); bf8_to_f32(v2, f2); bf8_to_f32(v3, f3);
#pragma unroll
    for (int j = 0; j < 8; ++j) a[j] += (f0[j] + f1[j]) + (f2[j] + f3[j]);
  }
  for (; i < e; ++i) {
    int4 v0 = *(const int4*)(x + (size_t)(int)ntl(&crow[i]) * DH + lm * 8);
    float f0[8];
    bf8_to_f32(v0, f0);
#pragma unroll
    for (int j = 0; j < 8; ++j) a[j] += f0[j];
  }
  float inv = 1.f / (float)(deg > 1 ? deg : 1);
  unsigned p0 = f2bf(a[0] * inv) | ((unsigned)f2bf(a[1] * inv) << 16);
  unsigned p1 = f2bf(a[2] * inv) | ((unsigned)f2bf(a[3] * inv) << 16);
  unsigned p2 = f2bf(a[4] * inv) | ((unsigned)f2bf(a[5] * inv) << 16);
  unsigned p3 = f2bf(a[6] * inv) | ((unsigned)f2bf(a[7] * inv) << 16);
  *(int4*)(out + (size_t)row * DH + lm * 8) = make_int4(p0, p1, p2, p3);
}

// ---------- SAGE update GEMM (no LDS): out = relu([A0|A1] @ WtT + bl) ----------
__global__ __launch_bounds__(256) void sage_mfma_k(
    const ushort_t* __restrict__ A0, const ushort_t* __restrict__ A1,
    const ushort_t* __restrict__ Wt, const float* __restrict__ bl,
    ushort_t* __restrict__ out, int N)
{
  const int wave = threadIdx.x >> 6;
  const int lane = threadIdx.x & 63;
  const int row0 = (blockIdx.x * 4 + wave) * 32;
  if (row0 >= N) return;
  const int lm = lane & 15;
  const int koff = (lane >> 4) * 8;

  size_t abase[2];
#pragma unroll
  for (int a = 0; a < 2; ++a) abase[a] = (size_t)(row0 + a * 16 + lm) * DH;

  f32x4 acc[2][8];
#pragma unroll
  for (int a = 0; a < 2; ++a)
#pragma unroll
    for (int nt = 0; nt < 8; ++nt) acc[a][nt] = (f32x4){0.f, 0.f, 0.f, 0.f};

#pragma unroll
  for (int ks = 0; ks < 8; ++ks) {
    short8 af[2];
#pragma unroll
    for (int a = 0; a < 2; ++a) {
      const ushort_t* p = (ks < 4) ? (A0 + abase[a] + ks * 32 + koff)
                                   : (A1 + abase[a] + (ks - 4) * 32 + koff);
      af[a] = *(const short8*)p;
    }
#pragma unroll
    for (int nt = 0; nt < 8; ++nt) {
      short8 bf = *(const short8*)&Wt[(nt * 16 + lm) * 256 + ks * 32 + koff];
      acc[0][nt] = __builtin_amdgcn_mfma_f32_16x16x32_bf16(af[0], bf, acc[0][nt], 0, 0, 0);
      acc[1][nt] = __builtin_amdgcn_mfma_f32_16x16x32_bf16(af[1], bf, acc[1][nt], 0, 0, 0);
    }
  }

  const int quad = lane >> 4;
#pragma unroll
  for (int nt = 0; nt < 8; ++nt) {
    int f = nt * 16 + lm;
    float bv = bl[f];
#pragma unroll
    for (int a = 0; a < 2; ++a) {
#pragma unroll
      for (int reg = 0; reg < 4; ++reg) {
        int r = row0 + a * 16 + quad * 4 + reg;
        out[(size_t)r * DH + f] = f2bf(fmaxf(acc[a][nt][reg] + bv, 0.f));
      }
    }
  }
}

// ---------- fused projection GEMMs: pu = ux@Wu, pm = mx@Wm ----------
__device__ __forceinline__ void proj_body(
    int lblk, const ushort_t* __restrict__ A, const ushort_t* __restrict__ Wt,
    int kofs, ushort_t* __restrict__ out, int N)
{
  const int wave = threadIdx.x >> 6;
  const int lane = threadIdx.x & 63;
  const int row0 = (lblk * 4 + wave) * 32;
  if (row0 >= N) return;
  const int lm = lane & 15;
  const int koff = (lane >> 4) * 8;

  size_t abase[2];
#pragma unroll
  for (int a = 0; a < 2; ++a) abase[a] = (size_t)(row0 + a * 16 + lm) * DH;

  f32x4 acc[2][8];
#pragma unroll
  for (int a = 0; a < 2; ++a)
#pragma unroll
    for (int nt = 0; nt < 8; ++nt) acc[a][nt] = (f32x4){0.f, 0.f, 0.f, 0.f};

#pragma unroll
  for (int ks = 0; ks < 4; ++ks) {
    short8 af[2];
#pragma unroll
    for (int a = 0; a < 2; ++a) af[a] = *(const short8*)(A + abase[a] + ks * 32 + koff);
#pragma unroll
    for (int nt = 0; nt < 8; ++nt) {
      short8 bf = *(const short8*)&Wt[(nt * 16 + lm) * 256 + kofs + ks * 32 + koff];
      acc[0][nt] = __builtin_amdgcn_mfma_f32_16x16x32_bf16(af[0], bf, acc[0][nt], 0, 0, 0);
      acc[1][nt] = __builtin_amdgcn_mfma_f32_16x16x32_bf16(af[1], bf, acc[1][nt], 0, 0, 0);
    }
  }

  const int quad = lane >> 4;
#pragma unroll
  for (int nt = 0; nt < 8; ++nt) {
    int f = nt * 16 + lm;
#pragma unroll
    for (int a = 0; a < 2; ++a) {
#pragma unroll
      for (int reg = 0; reg < 4; ++reg) {
        int r = row0 + a * 16 + quad * 4 + reg;
        out[(size_t)r * DH + f] = f2bf(acc[a][nt][reg]);
      }
    }
  }
}

__global__ __launch_bounds__(256) void proj2_k(
    const ushort_t* __restrict__ ux, const ushort_t* __restrict__ mx,
    const ushort_t* __restrict__ Wt, ushort_t* __restrict__ pu,
    ushort_t* __restrict__ pm, int gmU)
{
  if ((int)blockIdx.x < gmU) proj_body(blockIdx.x, ux, Wt, 0, pu, NUSR);
  else proj_body(blockIdx.x - gmU, mx, Wt, DH, pm, NMOV);
}

// ---------- edge-parallel predictor: quarter-wave per edge, EPQ=8 ----------
#define EPQ 8
__global__ __launch_bounds__(256) void ep_edge_k(
    const ushort_t* __restrict__ pu, const ushort_t* __restrict__ pm,
    const int* __restrict__ esrc, const int* __restrict__ edst,
    const float* __restrict__ SEP, const float* __restrict__ TEP,
    const float* __restrict__ p2W, const float* __restrict__ p2b,
    float* __restrict__ out, int nE)
{
  const int lm = threadIdx.x & 15;
  const long tq = ((long)blockIdx.x * 256 + threadIdx.x) >> 4;
  const int f0 = lm * 8;

  float S[8], T8[8], w2[8];
#pragma unroll
  for (int j = 0; j < 8; ++j) {
    S[j] = SEP[f0 + j];
    T8[j] = TEP[f0 + j];
    w2[j] = p2W[f0 + j];
  }
  const float bias2 = p2b[0];

  const long e0 = tq * EPQ;
#pragma unroll
  for (int i = 0; i < EPQ; ++i) {
    long e = e0 + i;
    if (e >= nE) break;
    int s = ntl(&esrc[e]), d = ntl(&edst[e]);
    int4 uv = *(const int4*)(pu + (size_t)s * DH + f0);
    int4 mv = *(const int4*)(pm + (size_t)d * DH + f0);
    float fu[8], fm[8];
    bf8_to_f32(uv, fu); bf8_to_f32(mv, fm);
    float p = 0.f;
#pragma unroll
    for (int j = 0; j < 8; ++j) {
      float h = fmaxf(fmaf(fu[j] + fm[j], S[j], T8[j]), 0.f);
      p = fmaf(h, w2[j], p);
    }
    p += __shfl_xor(p, 1, 16);
    p += __shfl_xor(p, 2, 16);
    p += __shfl_xor(p, 4, 16);
    p += __shfl_xor(p, 8, 16);
    if (lm == 0) out[e] = 4.f / (1.f + expf(-(p + bias2))) + 1.f;
  }
}

extern "C" void kernel_launch(void* const* d_in, const int* in_sizes, int n_in,
                              void* d_out, int out_size, void* d_ws, size_t ws_size,
                              hipStream_t stream)
{
  const float* user_feat = (const float*)d_in[0];
  const float* movie_feat = (const float*)d_in[1];
  const float* W_user = (const float*)d_in[2];
  const float* b_user = (const float*)d_in[3];
  const float* W_movie = (const float*)d_in[4];
  const float* b_movie = (const float*)d_in[5];
  const float* u2m1_Wl = (const float*)d_in[6];
  const float* u2m1_bl = (const float*)d_in[7];
  const float* u2m1_Wr = (const float*)d_in[8];
  const float* m2u1_Wl = (const float*)d_in[9];
  const float* m2u1_bl = (const float*)d_in[10];
  const float* m2u1_Wr = (const float*)d_in[11];
  const float* u2m2_Wl = (const float*)d_in[12];
  const float* u2m2_bl = (const float*)d_in[13];
  const float* u2m2_Wr = (const float*)d_in[14];
  const float* m2u2_Wl = (const float*)d_in[15];
  const float* m2u2_bl = (const float*)d_in[16];
  const float* m2u2_Wr = (const float*)d_in[17];
  const float* u2u_Wl = (const float*)d_in[18];
  const float* u2u_bl = (const float*)d_in[19];
  const float* u2u_Wr = (const float*)d_in[20];
  const float* p1_W = (const float*)d_in[21];
  const float* p1_b = (const float*)d_in[22];
  const float* bn_gamma = (const float*)d_in[23];
  const float* bn_beta = (const float*)d_in[24];
  const float* bn_mean = (const float*)d_in[25];
  const float* bn_var = (const float*)d_in[26];
  const float* p2_W = (const float*)d_in[27];
  const float* p2_b = (const float*)d_in[28];
  const int* rated_src = (const int*)d_in[29];
  const int* rated_dst = (const int*)d_in[30];
  const int* uu_src = (const int*)d_in[31];
  const int* uu_dst = (const int*)d_in[32];

  // ---- workspace layout (~86 MB) ----
  ushort_t* ux = (ushort_t*)d_ws;                       // NU*128
  ushort_t* mx = ux + (size_t)NUSR * DH;                // NM*128
  ushort_t* agg = mx + (size_t)NMOV * DH;               // NU*128 (reused as pu)
  ushort_t* pm = agg + (size_t)NUSR * DH;               // NM*128
  ushort_t* Wt = pm + (size_t)NMOV * DH;                // 6 * 32768
  ushort_t* WtU = Wt + 6 * 32768;                       // 128*64
  ushort_t* WtM = WtU + 8192;                           // 128*128
  float* SEP = (float*)(WtM + 16384);                   // 128
  float* TEP = SEP + DH;                                // 128
  int* col_m = (int*)(TEP + DH);                        // NMOV*CAPM ints
  ushort_t* col_u = (ushort_t*)(col_m + (size_t)NMOV * CAPM);   // NUSR*CAPU ushorts
  int* col_uu = (int*)(col_u + (size_t)NUSR * CAPU);    // NUSR*CAPUU ints
  int* cntbuf = col_uu + (size_t)NUSR * CAPUU;          // NMOV+2*NUSR (16B-aligned)
  int* cnt_m = cntbuf;
  int* cnt_u = cntbuf + NMOV;
  int* cnt_uu = cntbuf + NMOV + NUSR;

  ushort_t* Wt_u2m1 = Wt + 0 * 32768;
  ushort_t* Wt_m2u1 = Wt + 1 * 32768;
  ushort_t* Wt_u2m2 = Wt + 2 * 32768;
  ushort_t* Wt_m2u2 = Wt + 3 * 32768;
  ushort_t* Wt_u2u  = Wt + 4 * 32768;
  ushort_t* Wt_p1   = Wt + 5 * 32768;
  ushort_t* pu = agg;  // alias: agg dead after last sage layer

  // ---- fused weight prep + BN params + cnt zero ----
  PrepArgs pa;
  pa.Wl[0] = u2m1_Wl; pa.Wr[0] = u2m1_Wr;
  pa.Wl[1] = m2u1_Wl; pa.Wr[1] = m2u1_Wr;
  pa.Wl[2] = u2m2_Wl; pa.Wr[2] = u2m2_Wr;
  pa.Wl[3] = m2u2_Wl; pa.Wr[3] = m2u2_Wr;
  pa.Wl[4] = u2u_Wl;  pa.Wr[4] = u2u_Wr;
  pa.Wl[5] = p1_W;    pa.Wr[5] = p1_W + DH * DH;
  prep_all_k<<<865 + (NMOV + 2 * NUSR) / 1024 + 1, 256, 0, stream>>>(
      pa, Wt, W_user, W_movie, WtU, WtM,
      p1_b, bn_gamma, bn_beta, bn_mean, bn_var, SEP, TEP, cntbuf);

  // ---- fill (unpolluted), then input linears ----
  fill_k<<<NCB, 256, 0, stream>>>(
      rated_src, rated_dst, uu_src, uu_dst, cnt_m, cnt_u, cnt_uu,
      col_m, col_u, col_uu);
  lin2_k<<<GLU + GLM, 256, 0, stream>>>(
      user_feat, WtU, b_user, ux, movie_feat, WtM, b_movie, mx);

  // ---- 5 SAGE layers (separate agg + GEMM) ----
  const int gaM = (NMOV + 15) / 16, gaU = (NUSR + 15) / 16;
  const int gmM = (NMOV + 127) / 128, gmU = (NUSR + 127) / 128;
  // u2m1
  agg_mean4_k<int, CAPM, 16><<<gaM, 256, 0, stream>>>(ux, cnt_m, col_m, agg, NMOV);
  sage_mfma_k<<<gmM, 256, 0, stream>>>(agg, mx, Wt_u2m1, u2m1_bl, mx, NMOV);
  // m2u1
  agg_mean4_k<ushort_t, CAPU, 8><<<gaU, 256, 0, stream>>>(mx, cnt_u, col_u, agg, NUSR);
  sage_mfma_k<<<gmU, 256, 0, stream>>>(agg, ux, Wt_m2u1, m2u1_bl, ux, NUSR);
  // u2m2
  agg_mean4_k<int, CAPM, 16><<<gaM, 256, 0, stream>>>(ux, cnt_m, col_m, agg, NMOV);
  sage_mfma_k<<<gmM, 256, 0, stream>>>(agg, mx, Wt_u2m2, u2m2_bl, mx, NMOV);
  // m2u2
  agg_mean4_k<ushort_t, CAPU, 8><<<gaU, 256, 0, stream>>>(mx, cnt_u, col_u, agg, NUSR);
  sage_mfma_k<<<gmU, 256, 0, stream>>>(agg, ux, Wt_m2u2, m2u2_bl, ux, NUSR);
  // u2u
  agg_mean4_k<int, CAPUU, 8><<<gaU, 256, 0, stream>>>(ux, cnt_uu, col_uu, agg, NUSR);
  sage_mfma_k<<<gmU, 256, 0, stream>>>(agg, ux, Wt_u2u, u2u_bl, ux, NUSR);

  // ---- factored edge MLP ----
  proj2_k<<<gmU + gmM, 256, 0, stream>>>(ux, mx, Wt_p1, pu, pm, gmU);
  ep_edge_k<<<(NEDG + 127) / 128, 256, 0, stream>>>(
      pu, pm, rated_src, rated_dst, SEP, TEP, p2_W, p2_b, (float*)d_out, NEDG);
}

// Round 16
// 693.976 us; speedup vs baseline: 1.0810x; 1.0337x over previous
//
#include <hip/hip_runtime.h>
#include <cmath>

// SimpleHeteroGNN on MI355X — Round 16.
// R15 WIN (717us): fill/lin split confirmed L2-pollution theory.
// This round: fp8-e4m3 gather copies of node activations (ux8/mx8) — the 5
// gather-mean kernels are cache-line-service bound (R14: deeper unroll
// neutral); halving row bytes (256B->128B = 4->2 lines/row) halves line
// service. fp8 only on the aggregated-neighbor path; xdst/proj/ep stay bf16.
// HW converters: v_cvt_pk_f32_fp8 / v_cvt_pk_fp8_f32 (OCP e4m3, gfx950).

#define NUSR 100000
#define NMOV 20000
#define NEDG 1000000
#define NEUU 500000
#define DH 128

// padded adjacency capacities (degree means 50/10/5, std 7.1/3.2/2.2; guarded)
#define CAPM 96
#define CAPU 32
#define CAPUU 24

// XCD-binned fill geometry (mixed single-pass)
#define FCH 2048
#define NCH_R ((NEDG + FCH - 1) / FCH)  // 489
#define NCB (8 * NCH_R)                 // 3912 fill blocks
#define MRNG (NMOV / 8)
#define URNG (NUSR / 8)

// lin block ranges
#define GLU ((NUSR + 127) / 128)        // 782
#define GLM ((NMOV + 127) / 128)        // 157

typedef unsigned short ushort_t;
typedef unsigned char uchar_t;
typedef __attribute__((ext_vector_type(8))) short short8;
typedef __attribute__((ext_vector_type(4))) float f32x4;
typedef __attribute__((ext_vector_type(2))) float f32x2;

__device__ __forceinline__ ushort_t f2bf(float f) {
  unsigned u = __float_as_uint(f);
  u += 0x7FFFu + ((u >> 16) & 1u);
  return (ushort_t)(u >> 16);
}
__device__ __forceinline__ uchar_t f2fp8(float v) {
  return (uchar_t)(__builtin_amdgcn_cvt_pk_fp8_f32(v, v, 0, false) & 0xFF);
}
__device__ __forceinline__ void fp8x8_to_f32(uint2 v, float* f) {
  f32x2 a = __builtin_amdgcn_cvt_pk_f32_fp8((int)v.x, false);
  f32x2 b = __builtin_amdgcn_cvt_pk_f32_fp8((int)v.x, true);
  f32x2 c = __builtin_amdgcn_cvt_pk_f32_fp8((int)v.y, false);
  f32x2 d = __builtin_amdgcn_cvt_pk_f32_fp8((int)v.y, true);
  f[0] = a.x; f[1] = a.y; f[2] = b.x; f[3] = b.y;
  f[4] = c.x; f[5] = c.y; f[6] = d.x; f[7] = d.y;
}
__device__ __forceinline__ int ntl(const int* p) { return __builtin_nontemporal_load(p); }
__device__ __forceinline__ ushort_t ntl(const ushort_t* p) { return __builtin_nontemporal_load(p); }

// ---------- fused weight prep + BN params + cnt zero ----------
struct PrepArgs {
  const float* Wl[6];
  const float* Wr[6];
};
__global__ __launch_bounds__(256) void prep_all_k(
    PrepArgs pa, ushort_t* __restrict__ Wt,
    const float* __restrict__ W_user, const float* __restrict__ W_movie,
    ushort_t* __restrict__ WtU, ushort_t* __restrict__ WtM,
    const float* __restrict__ p1b, const float* __restrict__ gamma,
    const float* __restrict__ beta, const float* __restrict__ mean,
    const float* __restrict__ var,
    float* __restrict__ SEP, float* __restrict__ TEP,
    int* __restrict__ cntbuf)
{
  int blk = blockIdx.x;
  if (blk < 768) {
    int wi = blk >> 7;
    int idx = (blk & 127) * 256 + threadIdx.x;
    int n = idx >> 8, k = idx & 255;
    const float* Wl = pa.Wl[wi];
    const float* Wr = pa.Wr[wi];
    float v = (k < DH) ? Wl[k * DH + n] : Wr[(k - DH) * DH + n];
    Wt[(size_t)wi * 32768 + n * 256 + k] = f2bf(v);
  } else if (blk < 800) {
    int idx = (blk - 768) * 256 + threadIdx.x;
    int n = idx >> 6, k = idx & 63;
    WtU[n * 64 + k] = f2bf(W_user[k * DH + n]);
  } else if (blk < 864) {
    int idx = (blk - 800) * 256 + threadIdx.x;
    int n = idx >> 7, k = idx & 127;
    WtM[n * 128 + k] = f2bf(W_movie[k * DH + n]);
  } else if (blk == 864) {
    int f = threadIdx.x;
    if (f < DH) {
      float sc = gamma[f] * rsqrtf(var[f] + 1e-5f);
      SEP[f] = sc;
      TEP[f] = (p1b[f] - mean[f]) * sc + beta[f];
    }
  } else {
    int idx = (blk - 865) * 256 + threadIdx.x;  // int4 index
    if (idx < (NMOV + 2 * NUSR) / 4) ((int4*)cntbuf)[idx] = make_int4(0, 0, 0, 0);
  }
}

// ---------- XCD-binned mixed direct fill (atomics + col stores ONLY) ----------
__global__ __launch_bounds__(256) void fill_k(
    const int* __restrict__ rsrc, const int* __restrict__ rdst,
    const int* __restrict__ usrc, const int* __restrict__ udst,
    int* __restrict__ cnt_m, int* __restrict__ cnt_u, int* __restrict__ cnt_uu,
    int* __restrict__ col_m, ushort_t* __restrict__ col_u, int* __restrict__ col_uu)
{
  const int xr = blockIdx.x & 7;
  const int c = blockIdx.x >> 3;
  const int mlo = xr * MRNG, mhi = mlo + MRNG;
  const int ulo = xr * URNG, uhi = ulo + URNG;
  const int base = c * FCH;
#pragma unroll
  for (int i = 0; i < 8; ++i) {
    int e = base + i * 256 + threadIdx.x;
    if (e < NEDG) {
      int s = ntl(&rsrc[e]), d = ntl(&rdst[e]);
      if (d >= mlo && d < mhi) {
        int o = atomicAdd(&cnt_m[d], 1);
        if (o < CAPM) col_m[d * CAPM + o] = s;
      }
      if (s >= ulo && s < uhi) {
        int o = atomicAdd(&cnt_u[s], 1);
        if (o < CAPU) col_u[s * CAPU + o] = (ushort_t)d;
      }
    }
    if (e < NEUU) {
      int s = ntl(&usrc[e]), d = ntl(&udst[e]);
      if (d >= ulo && d < uhi) {
        int o = atomicAdd(&cnt_uu[d], 1);
        if (o < CAPUU) col_uu[d * CAPUU + o] = s;
      }
    }
  }
}

// ---------- lin GEMM body (fp32 A converted in-register; bf16 + fp8 out) ----------
template <int K>
__device__ __forceinline__ void lin_body(
    int lblk, const float* __restrict__ X, const ushort_t* __restrict__ Wt,
    const float* __restrict__ b, ushort_t* __restrict__ Y,
    uchar_t* __restrict__ Y8, int N)
{
  const int wave = threadIdx.x >> 6;
  const int lane = threadIdx.x & 63;
  const int row0 = (lblk * 4 + wave) * 32;
  if (row0 >= N) return;
  const int lm = lane & 15;
  const int koff = (lane >> 4) * 8;

  f32x4 acc[2][8];
#pragma unroll
  for (int a = 0; a < 2; ++a)
#pragma unroll
    for (int nt = 0; nt < 8; ++nt) acc[a][nt] = (f32x4){0.f, 0.f, 0.f, 0.f};

#pragma unroll
  for (int ks = 0; ks < K / 32; ++ks) {
    short8 af[2];
#pragma unroll
    for (int a = 0; a < 2; ++a) {
      const float* p = X + (size_t)(row0 + a * 16 + lm) * K + ks * 32 + koff;
      float4 v0 = *(const float4*)p;
      float4 v1 = *(const float4*)(p + 4);
      short8 s;
      s[0] = (short)f2bf(v0.x); s[1] = (short)f2bf(v0.y);
      s[2] = (short)f2bf(v0.z); s[3] = (short)f2bf(v0.w);
      s[4] = (short)f2bf(v1.x); s[5] = (short)f2bf(v1.y);
      s[6] = (short)f2bf(v1.z); s[7] = (short)f2bf(v1.w);
      af[a] = s;
    }
#pragma unroll
    for (int nt = 0; nt < 8; ++nt) {
      short8 bf = *(const short8*)&Wt[(nt * 16 + lm) * K + ks * 32 + koff];
      acc[0][nt] = __builtin_amdgcn_mfma_f32_16x16x32_bf16(af[0], bf, acc[0][nt], 0, 0, 0);
      acc[1][nt] = __builtin_amdgcn_mfma_f32_16x16x32_bf16(af[1], bf, acc[1][nt], 0, 0, 0);
    }
  }

  const int quad = lane >> 4;
#pragma unroll
  for (int nt = 0; nt < 8; ++nt) {
    int f = nt * 16 + lm;
    float bv = b[f];
#pragma unroll
    for (int a = 0; a < 2; ++a) {
#pragma unroll
      for (int reg = 0; reg < 4; ++reg) {
        int r = row0 + a * 16 + quad * 4 + reg;
        float val = fmaxf(acc[a][nt][reg] + bv, 0.f);
        Y[(size_t)r * DH + f] = f2bf(val);
        Y8[(size_t)r * DH + f] = f2fp8(val);
      }
    }
  }
}

// ---------- both input linears in one dispatch ----------
__global__ __launch_bounds__(256) void lin2_k(
    const float* __restrict__ user_feat, const ushort_t* __restrict__ WtU,
    const float* __restrict__ b_user, ushort_t* __restrict__ ux, uchar_t* __restrict__ ux8,
    const float* __restrict__ movie_feat, const ushort_t* __restrict__ WtM,
    const float* __restrict__ b_movie, ushort_t* __restrict__ mx, uchar_t* __restrict__ mx8)
{
  const int blk = blockIdx.x;
  if (blk < GLU) lin_body<64>(blk, user_feat, WtU, b_user, ux, ux8, NUSR);
  else lin_body<128>(blk - GLU, movie_feat, WtM, b_movie, mx, mx8, NMOV);
}

// ---------- gather-mean over padded adjacency, fp8 source: 4 rows/wave ----------
template <typename CT, int CAP, int UNR>
__global__ __launch_bounds__(256) void agg_mean4_k(
    const uchar_t* __restrict__ x8, const int* __restrict__ cnt,
    const CT* __restrict__ col, ushort_t* __restrict__ out, int N)
{
  const int wave = threadIdx.x >> 6;
  const int lane = threadIdx.x & 63;
  const int lm = lane & 15, q = lane >> 4;
  const int row = blockIdx.x * 16 + wave * 4 + q;
  if (row >= N) return;
  const int deg = cnt[row];
  const int e = (deg < CAP) ? deg : CAP;
  const CT* crow = col + (size_t)row * CAP;
  float a[8];
#pragma unroll
  for (int j = 0; j < 8; ++j) a[j] = 0.f;
  int i = 0;
  if (UNR >= 16) {
    for (; i + 15 < e; i += 16) {
      uint2 v[16];
#pragma unroll
      for (int u = 0; u < 16; ++u) {
        int s = (int)ntl(&crow[i + u]);
        v[u] = *(const uint2*)(x8 + (size_t)s * DH + lm * 8);
      }
#pragma unroll
      for (int u = 0; u < 16; ++u) {
        float f0[8];
        fp8x8_to_f32(v[u], f0);
#pragma unroll
        for (int j = 0; j < 8; ++j) a[j] += f0[j];
      }
    }
  }
  if (UNR >= 8) {
    for (; i + 7 < e; i += 8) {
      uint2 v[8];
#pragma unroll
      for (int u = 0; u < 8; ++u) {
        int s = (int)ntl(&crow[i + u]);
        v[u] = *(const uint2*)(x8 + (size_t)s * DH + lm * 8);
      }
#pragma unroll
      for (int u = 0; u < 8; ++u) {
        float f0[8];
        fp8x8_to_f32(v[u], f0);
#pragma unroll
        for (int j = 0; j < 8; ++j) a[j] += f0[j];
      }
    }
  }
  for (; i + 3 < e; i += 4) {
    uint2 v0, v1, v2, v3;
    int s0 = (int)ntl(&crow[i]), s1 = (int)ntl(&crow[i + 1]);
    int s2 = (int)ntl(&crow[i + 2]), s3 = (int)ntl(&crow[i + 3]);
    v0 = *(const uint2*)(x8 + (size_t)s0 * DH + lm * 8);
    v1 = *(const uint2*)(x8 + (size_t)s1 * DH + lm * 8);
    v2 = *(const uint2*)(x8 + (size_t)s2 * DH + lm * 8);
    v3 = *(const uint2*)(x8 + (size_t)s3 * DH + lm * 8);
    float f0[8], f1[8], f2[8], f3[8];
    fp8x8_to_f32(v0, f0); fp8x8_to_f32(v1, f1);
    fp8x8_to_f32(v2, f2); fp8x8_to_f32(v3, f3);
#pragma unroll
    for (int j = 0; j < 8; ++j) a[j] += (f0[j] + f1[j]) + (f2[j] + f3[j]);
  }
  for (; i < e; ++i) {
    uint2 v0 = *(const uint2*)(x8 + (size_t)(int)ntl(&crow[i]) * DH + lm * 8);
    float f0[8];
    fp8x8_to_f32(v0, f0);
#pragma unroll
    for (int j = 0; j < 8; ++j) a[j] += f0[j];
  }
  float inv = 1.f / (float)(deg > 1 ? deg : 1);
  unsigned p0 = f2bf(a[0] * inv) | ((unsigned)f2bf(a[1] * inv) << 16);
  unsigned p1 = f2bf(a[2] * inv) | ((unsigned)f2bf(a[3] * inv) << 16);
  unsigned p2 = f2bf(a[4] * inv) | ((unsigned)f2bf(a[5] * inv) << 16);
  unsigned p3 = f2bf(a[6] * inv) | ((unsigned)f2bf(a[7] * inv) << 16);
  *(int4*)(out + (size_t)row * DH + lm * 8) = make_int4(p0, p1, p2, p3);
}

// ---------- SAGE update GEMM: out = relu([A0|A1] @ WtT + bl), bf16 + opt fp8 ----------
__global__ __launch_bounds__(256) void sage_mfma_k(
    const ushort_t* __restrict__ A0, const ushort_t* __restrict__ A1,
    const ushort_t* __restrict__ Wt, const float* __restrict__ bl,
    ushort_t* __restrict__ out, uchar_t* __restrict__ out8, int N)
{
  const int wave = threadIdx.x >> 6;
  const int lane = threadIdx.x & 63;
  const int row0 = (blockIdx.x * 4 + wave) * 32;
  if (row0 >= N) return;
  const int lm = lane & 15;
  const int koff = (lane >> 4) * 8;

  size_t abase[2];
#pragma unroll
  for (int a = 0; a < 2; ++a) abase[a] = (size_t)(row0 + a * 16 + lm) * DH;

  f32x4 acc[2][8];
#pragma unroll
  for (int a = 0; a < 2; ++a)
#pragma unroll
    for (int nt = 0; nt < 8; ++nt) acc[a][nt] = (f32x4){0.f, 0.f, 0.f, 0.f};

#pragma unroll
  for (int ks = 0; ks < 8; ++ks) {
    short8 af[2];
#pragma unroll
    for (int a = 0; a < 2; ++a) {
      const ushort_t* p = (ks < 4) ? (A0 + abase[a] + ks * 32 + koff)
                                   : (A1 + abase[a] + (ks - 4) * 32 + koff);
      af[a] = *(const short8*)p;
    }
#pragma unroll
    for (int nt = 0; nt < 8; ++nt) {
      short8 bf = *(const short8*)&Wt[(nt * 16 + lm) * 256 + ks * 32 + koff];
      acc[0][nt] = __builtin_amdgcn_mfma_f32_16x16x32_bf16(af[0], bf, acc[0][nt], 0, 0, 0);
      acc[1][nt] = __builtin_amdgcn_mfma_f32_16x16x32_bf16(af[1], bf, acc[1][nt], 0, 0, 0);
    }
  }

  const int quad = lane >> 4;
#pragma unroll
  for (int nt = 0; nt < 8; ++nt) {
    int f = nt * 16 + lm;
    float bv = bl[f];
#pragma unroll
    for (int a = 0; a < 2; ++a) {
#pragma unroll
      for (int reg = 0; reg < 4; ++reg) {
        int r = row0 + a * 16 + quad * 4 + reg;
        float val = fmaxf(acc[a][nt][reg] + bv, 0.f);
        out[(size_t)r * DH + f] = f2bf(val);
        if (out8) out8[(size_t)r * DH + f] = f2fp8(val);
      }
    }
  }
}

// ---------- fused projection GEMMs: pu = ux@Wu, pm = mx@Wm ----------
__device__ __forceinline__ void proj_body(
    int lblk, const ushort_t* __restrict__ A, const ushort_t* __restrict__ Wt,
    int kofs, ushort_t* __restrict__ out, int N)
{
  const int wave = threadIdx.x >> 6;
  const int lane = threadIdx.x & 63;
  const int row0 = (lblk * 4 + wave) * 32;
  if (row0 >= N) return;
  const int lm = lane & 15;
  const int koff = (lane >> 4) * 8;

  size_t abase[2];
#pragma unroll
  for (int a = 0; a < 2; ++a) abase[a] = (size_t)(row0 + a * 16 + lm) * DH;

  f32x4 acc[2][8];
#pragma unroll
  for (int a = 0; a < 2; ++a)
#pragma unroll
    for (int nt = 0; nt < 8; ++nt) acc[a][nt] = (f32x4){0.f, 0.f, 0.f, 0.f};

#pragma unroll
  for (int ks = 0; ks < 4; ++ks) {
    short8 af[2];
#pragma unroll
    for (int a = 0; a < 2; ++a) af[a] = *(const short8*)(A + abase[a] + ks * 32 + koff);
#pragma unroll
    for (int nt = 0; nt < 8; ++nt) {
      short8 bf = *(const short8*)&Wt[(nt * 16 + lm) * 256 + kofs + ks * 32 + koff];
      acc[0][nt] = __builtin_amdgcn_mfma_f32_16x16x32_bf16(af[0], bf, acc[0][nt], 0, 0, 0);
      acc[1][nt] = __builtin_amdgcn_mfma_f32_16x16x32_bf16(af[1], bf, acc[1][nt], 0, 0, 0);
    }
  }

  const int quad = lane >> 4;
#pragma unroll
  for (int nt = 0; nt < 8; ++nt) {
    int f = nt * 16 + lm;
#pragma unroll
    for (int a = 0; a < 2; ++a) {
#pragma unroll
      for (int reg = 0; reg < 4; ++reg) {
        int r = row0 + a * 16 + quad * 4 + reg;
        out[(size_t)r * DH + f] = f2bf(acc[a][nt][reg]);
      }
    }
  }
}

__global__ __launch_bounds__(256) void proj2_k(
    const ushort_t* __restrict__ ux, const ushort_t* __restrict__ mx,
    const ushort_t* __restrict__ Wt, ushort_t* __restrict__ pu,
    ushort_t* __restrict__ pm, int gmU)
{
  if ((int)blockIdx.x < gmU) proj_body(blockIdx.x, ux, Wt, 0, pu, NUSR);
  else proj_body(blockIdx.x - gmU, mx, Wt, DH, pm, NMOV);
}

// ---------- edge-parallel predictor: quarter-wave per edge, EPQ=8 ----------
#define EPQ 8
__global__ __launch_bounds__(256) void ep_edge_k(
    const ushort_t* __restrict__ pu, const ushort_t* __restrict__ pm,
    const int* __restrict__ esrc, const int* __restrict__ edst,
    const float* __restrict__ SEP, const float* __restrict__ TEP,
    const float* __restrict__ p2W, const float* __restrict__ p2b,
    float* __restrict__ out, int nE)
{
  const int lm = threadIdx.x & 15;
  const long tq = ((long)blockIdx.x * 256 + threadIdx.x) >> 4;
  const int f0 = lm * 8;

  float S[8], T8[8], w2[8];
#pragma unroll
  for (int j = 0; j < 8; ++j) {
    S[j] = SEP[f0 + j];
    T8[j] = TEP[f0 + j];
    w2[j] = p2W[f0 + j];
  }
  const float bias2 = p2b[0];

  const long e0 = tq * EPQ;
#pragma unroll
  for (int i = 0; i < EPQ; ++i) {
    long e = e0 + i;
    if (e >= nE) break;
    int s = ntl(&esrc[e]), d = ntl(&edst[e]);
    int4 uv = *(const int4*)(pu + (size_t)s * DH + f0);
    int4 mv = *(const int4*)(pm + (size_t)d * DH + f0);
    float fu[8], fm[8];
    {
      unsigned a0 = (unsigned)uv.x, b0 = (unsigned)uv.y, c0 = (unsigned)uv.z, d0 = (unsigned)uv.w;
      fu[0] = __uint_as_float(a0 << 16); fu[1] = __uint_as_float(a0 & 0xFFFF0000u);
      fu[2] = __uint_as_float(b0 << 16); fu[3] = __uint_as_float(b0 & 0xFFFF0000u);
      fu[4] = __uint_as_float(c0 << 16); fu[5] = __uint_as_float(c0 & 0xFFFF0000u);
      fu[6] = __uint_as_float(d0 << 16); fu[7] = __uint_as_float(d0 & 0xFFFF0000u);
      unsigned a1 = (unsigned)mv.x, b1 = (unsigned)mv.y, c1 = (unsigned)mv.z, d1 = (unsigned)mv.w;
      fm[0] = __uint_as_float(a1 << 16); fm[1] = __uint_as_float(a1 & 0xFFFF0000u);
      fm[2] = __uint_as_float(b1 << 16); fm[3] = __uint_as_float(b1 & 0xFFFF0000u);
      fm[4] = __uint_as_float(c1 << 16); fm[5] = __uint_as_float(c1 & 0xFFFF0000u);
      fm[6] = __uint_as_float(d1 << 16); fm[7] = __uint_as_float(d1 & 0xFFFF0000u);
    }
    float p = 0.f;
#pragma unroll
    for (int j = 0; j < 8; ++j) {
      float h = fmaxf(fmaf(fu[j] + fm[j], S[j], T8[j]), 0.f);
      p = fmaf(h, w2[j], p);
    }
    p += __shfl_xor(p, 1, 16);
    p += __shfl_xor(p, 2, 16);
    p += __shfl_xor(p, 4, 16);
    p += __shfl_xor(p, 8, 16);
    if (lm == 0) out[e] = 4.f / (1.f + expf(-(p + bias2))) + 1.f;
  }
}

extern "C" void kernel_launch(void* const* d_in, const int* in_sizes, int n_in,
                              void* d_out, int out_size, void* d_ws, size_t ws_size,
                              hipStream_t stream)
{
  const float* user_feat = (const float*)d_in[0];
  const float* movie_feat = (const float*)d_in[1];
  const float* W_user = (const float*)d_in[2];
  const float* b_user = (const float*)d_in[3];
  const float* W_movie = (const float*)d_in[4];
  const float* b_movie = (const float*)d_in[5];
  const float* u2m1_Wl = (const float*)d_in[6];
  const float* u2m1_bl = (const float*)d_in[7];
  const float* u2m1_Wr = (const float*)d_in[8];
  const float* m2u1_Wl = (const float*)d_in[9];
  const float* m2u1_bl = (const float*)d_in[10];
  const float* m2u1_Wr = (const float*)d_in[11];
  const float* u2m2_Wl = (const float*)d_in[12];
  const float* u2m2_bl = (const float*)d_in[13];
  const float* u2m2_Wr = (const float*)d_in[14];
  const float* m2u2_Wl = (const float*)d_in[15];
  const float* m2u2_bl = (const float*)d_in[16];
  const float* m2u2_Wr = (const float*)d_in[17];
  const float* u2u_Wl = (const float*)d_in[18];
  const float* u2u_bl = (const float*)d_in[19];
  const float* u2u_Wr = (const float*)d_in[20];
  const float* p1_W = (const float*)d_in[21];
  const float* p1_b = (const float*)d_in[22];
  const float* bn_gamma = (const float*)d_in[23];
  const float* bn_beta = (const float*)d_in[24];
  const float* bn_mean = (const float*)d_in[25];
  const float* bn_var = (const float*)d_in[26];
  const float* p2_W = (const float*)d_in[27];
  const float* p2_b = (const float*)d_in[28];
  const int* rated_src = (const int*)d_in[29];
  const int* rated_dst = (const int*)d_in[30];
  const int* uu_src = (const int*)d_in[31];
  const int* uu_dst = (const int*)d_in[32];

  // ---- workspace layout (~102 MB; R1 used 113 MB so ws fits) ----
  ushort_t* ux = (ushort_t*)d_ws;                       // NU*128 bf16
  ushort_t* mx = ux + (size_t)NUSR * DH;                // NM*128
  ushort_t* agg = mx + (size_t)NMOV * DH;               // NU*128 (reused as pu)
  ushort_t* pm = agg + (size_t)NUSR * DH;               // NM*128
  ushort_t* Wt = pm + (size_t)NMOV * DH;                // 6 * 32768
  ushort_t* WtU = Wt + 6 * 32768;                       // 128*64
  ushort_t* WtM = WtU + 8192;                           // 128*128
  float* SEP = (float*)(WtM + 16384);                   // 128
  float* TEP = SEP + DH;                                // 128
  int* col_m = (int*)(TEP + DH);                        // NMOV*CAPM ints
  ushort_t* col_u = (ushort_t*)(col_m + (size_t)NMOV * CAPM);   // NUSR*CAPU ushorts
  int* col_uu = (int*)(col_u + (size_t)NUSR * CAPU);    // NUSR*CAPUU ints
  int* cntbuf = col_uu + (size_t)NUSR * CAPUU;          // NMOV+2*NUSR (16B-aligned)
  uchar_t* ux8 = (uchar_t*)(cntbuf + (NMOV + 2 * NUSR));// NU*128 fp8
  uchar_t* mx8 = ux8 + (size_t)NUSR * DH;               // NM*128 fp8
  int* cnt_m = cntbuf;
  int* cnt_u = cntbuf + NMOV;
  int* cnt_uu = cntbuf + NMOV + NUSR;

  ushort_t* Wt_u2m1 = Wt + 0 * 32768;
  ushort_t* Wt_m2u1 = Wt + 1 * 32768;
  ushort_t* Wt_u2m2 = Wt + 2 * 32768;
  ushort_t* Wt_m2u2 = Wt + 3 * 32768;
  ushort_t* Wt_u2u  = Wt + 4 * 32768;
  ushort_t* Wt_p1   = Wt + 5 * 32768;
  ushort_t* pu = agg;  // alias: agg dead after last sage layer

  // ---- fused weight prep + BN params + cnt zero ----
  PrepArgs pa;
  pa.Wl[0] = u2m1_Wl; pa.Wr[0] = u2m1_Wr;
  pa.Wl[1] = m2u1_Wl; pa.Wr[1] = m2u1_Wr;
  pa.Wl[2] = u2m2_Wl; pa.Wr[2] = u2m2_Wr;
  pa.Wl[3] = m2u2_Wl; pa.Wr[3] = m2u2_Wr;
  pa.Wl[4] = u2u_Wl;  pa.Wr[4] = u2u_Wr;
  pa.Wl[5] = p1_W;    pa.Wr[5] = p1_W + DH * DH;
  prep_all_k<<<865 + (NMOV + 2 * NUSR) / 1024 + 1, 256, 0, stream>>>(
      pa, Wt, W_user, W_movie, WtU, WtM,
      p1_b, bn_gamma, bn_beta, bn_mean, bn_var, SEP, TEP, cntbuf);

  // ---- fill (unpolluted), then input linears (bf16 + fp8 out) ----
  fill_k<<<NCB, 256, 0, stream>>>(
      rated_src, rated_dst, uu_src, uu_dst, cnt_m, cnt_u, cnt_uu,
      col_m, col_u, col_uu);
  lin2_k<<<GLU + GLM, 256, 0, stream>>>(
      user_feat, WtU, b_user, ux, ux8, movie_feat, WtM, b_movie, mx, mx8);

  // ---- 5 SAGE layers (fp8 gather + bf16 MFMA) ----
  const int gaM = (NMOV + 15) / 16, gaU = (NUSR + 15) / 16;
  const int gmM = (NMOV + 127) / 128, gmU = (NUSR + 127) / 128;
  // u2m1: gather ux8 -> agg; update mx (+mx8, needed by m2u1 agg)
  agg_mean4_k<int, CAPM, 16><<<gaM, 256, 0, stream>>>(ux8, cnt_m, col_m, agg, NMOV);
  sage_mfma_k<<<gmM, 256, 0, stream>>>(agg, mx, Wt_u2m1, u2m1_bl, mx, mx8, NMOV);
  // m2u1: gather mx8 -> agg; update ux (+ux8, needed by u2m2 agg)
  agg_mean4_k<ushort_t, CAPU, 8><<<gaU, 256, 0, stream>>>(mx8, cnt_u, col_u, agg, NUSR);
  sage_mfma_k<<<gmU, 256, 0, stream>>>(agg, ux, Wt_m2u1, m2u1_bl, ux, ux8, NUSR);
  // u2m2
  agg_mean4_k<int, CAPM, 16><<<gaM, 256, 0, stream>>>(ux8, cnt_m, col_m, agg, NMOV);
  sage_mfma_k<<<gmM, 256, 0, stream>>>(agg, mx, Wt_u2m2, u2m2_bl, mx, mx8, NMOV);
  // m2u2
  agg_mean4_k<ushort_t, CAPU, 8><<<gaU, 256, 0, stream>>>(mx8, cnt_u, col_u, agg, NUSR);
  sage_mfma_k<<<gmU, 256, 0, stream>>>(agg, ux, Wt_m2u2, m2u2_bl, ux, ux8, NUSR);
  // u2u: final user layer; fp8 copy no longer needed afterwards
  agg_mean4_k<int, CAPUU, 8><<<gaU, 256, 0, stream>>>(ux8, cnt_uu, col_uu, agg, NUSR);
  sage_mfma_k<<<gmU, 256, 0, stream>>>(agg, ux, Wt_u2u, u2u_bl, ux, (uchar_t*)nullptr, NUSR);

  // ---- factored edge MLP (bf16 throughout) ----
  proj2_k<<<gmU + gmM, 256, 0, stream>>>(ux, mx, Wt_p1, pu, pm, gmU);
  ep_edge_k<<<(NEDG + 127) / 128, 256, 0, stream>>>(
      pu, pm, rated_src, rated_dst, SEP, TEP, p2_W, p2_b, (float*)d_out, NEDG);
}